// Round 2
// baseline (504.736 us; speedup 1.0000x reference)
//
#include <hip/hip_runtime.h>

typedef unsigned short u16;
typedef unsigned int   u32;

using bf16x8 = __attribute__((ext_vector_type(8))) short;
using f32x4  = __attribute__((ext_vector_type(4))) float;

#define MFMA16(A, B, C) __builtin_amdgcn_mfma_f32_16x16x32_bf16((A), (B), (C), 0, 0, 0)

static __device__ __forceinline__ u16 f2b(float f) {
    u32 u = __builtin_bit_cast(u32, f);
    u32 r = (u + 0x7FFFu + ((u >> 16) & 1u)) >> 16;
    return (u16)r;
}
// two float4 chunks -> 8 bf16
static __device__ __forceinline__ bf16x8 cvt8(f32x4 a, f32x4 b) {
    bf16x8 r;
    r[0] = (short)f2b(a[0]); r[1] = (short)f2b(a[1]);
    r[2] = (short)f2b(a[2]); r[3] = (short)f2b(a[3]);
    r[4] = (short)f2b(b[0]); r[5] = (short)f2b(b[1]);
    r[6] = (short)f2b(b[2]); r[7] = (short)f2b(b[3]);
    return r;
}

// ---------------------------------------------------------------------------
// K0: weight prep (fp32 in -> bf16 out).
// WcatT[n=h*256+c][i] = (1/8) * sum_d Wq[i][h*64+d]*Wk[c][h*64+d]   ([n][k] layout)
// WresT/WvT/W1T/W2T = transposes to [n][k] so MFMA B-frags are 16B direct loads.
__global__ __launch_bounds__(256) void k0_prep(
    const float* __restrict__ Wq, const float* __restrict__ Wk,
    const float* __restrict__ Wv, const float* __restrict__ Wres,
    const float* __restrict__ W1, const float* __restrict__ W2,
    u16* __restrict__ WcatT, u16* __restrict__ WresT,
    u16* __restrict__ WvT, u16* __restrict__ W1T, u16* __restrict__ W2T)
{
    int t = blockIdx.x * 256 + threadIdx.x;
    if (t < 131072) {
        int n = t >> 7, i = t & 127;
        int h = n >> 8, c = n & 255;
        const float* wq = Wq + i * 256 + h * 64;
        const float* wk = Wk + c * 256 + h * 64;
        float acc = 0.f;
        #pragma unroll 8
        for (int d = 0; d < 64; ++d) acc += wq[d] * wk[d];
        WcatT[t] = f2b(acc * 0.125f);            // softmax 1/sqrt(64) folded in
    } else if (t < 163840) {
        int o = t - 131072; int n = o >> 7, i = o & 127;
        WresT[o] = f2b(Wres[i * 256 + n]);
    } else if (t < 229376) {
        int o = t - 163840; int n = o >> 8, c = o & 255;
        WvT[o] = f2b(Wv[c * 256 + n]);
    } else if (t < 294912) {
        int o = t - 229376; int n = o >> 8, c = o & 255;
        W1T[o] = f2b(W1[c * 256 + n]);
    } else {
        int o = t - 294912; int n = o >> 8, c = o & 255;
        W2T[o] = f2b(W2[c * 256 + n]);
    }
}

// ---------------------------------------------------------------------------
// K1: qkvec[16384,1024] = x_u[16384,128] @ Wcat[128,1024]   (bf16 MFMA, K=128)
__global__ __launch_bounds__(256) void k1_qkvec(
    const float* __restrict__ xu, const u16* __restrict__ WcatT,
    u16* __restrict__ qkvec)
{
    __shared__ __align__(16) u16 As[128][136];    // +8 pad
    const int m0 = blockIdx.x * 128, n0 = blockIdx.y * 128;
    const int t = threadIdx.x;
    #pragma unroll
    for (int i = 0; i < 8; ++i) {
        int c = t + i * 256;                      // 2048 groups of 8 floats
        int row = c >> 4, ch = c & 15;
        const float* src = xu + (size_t)(m0 + row) * 128 + ch * 8;
        f32x4 a = *(const f32x4*)src;
        f32x4 b = *(const f32x4*)(src + 4);
        *(bf16x8*)&As[row][ch * 8] = cvt8(a, b);
    }
    __syncthreads();
    const int lane = t & 63, wave = t >> 6;
    const int quad = lane >> 4, l16 = lane & 15;
    const int mh = (wave >> 1) * 64, nh = (wave & 1) * 64;
    f32x4 zz = {0.f, 0.f, 0.f, 0.f};
    f32x4 acc[4][4];
    #pragma unroll
    for (int mt = 0; mt < 4; ++mt)
        #pragma unroll
        for (int nt = 0; nt < 4; ++nt) acc[mt][nt] = zz;
    #pragma unroll
    for (int ks = 0; ks < 4; ++ks) {
        bf16x8 a[4], b[4];
        #pragma unroll
        for (int mt = 0; mt < 4; ++mt)
            a[mt] = *(const bf16x8*)&As[mh + mt * 16 + l16][ks * 32 + quad * 8];
        #pragma unroll
        for (int nt = 0; nt < 4; ++nt)
            b[nt] = *(const bf16x8*)(WcatT + (size_t)(n0 + nh + nt * 16 + l16) * 128 + ks * 32 + quad * 8);
        #pragma unroll
        for (int mt = 0; mt < 4; ++mt)
            #pragma unroll
            for (int nt = 0; nt < 4; ++nt)
                acc[mt][nt] = MFMA16(a[mt], b[nt], acc[mt][nt]);
    }
    #pragma unroll
    for (int mt = 0; mt < 4; ++mt)
        #pragma unroll
        for (int nt = 0; nt < 4; ++nt) {
            int col = n0 + nh + nt * 16 + l16;
            #pragma unroll
            for (int r = 0; r < 4; ++r) {
                int row = m0 + mh + mt * 16 + quad * 4 + r;
                qkvec[(size_t)row * 1024 + col] = f2b(acc[mt][nt][r]);
            }
        }
}

// ---------------------------------------------------------------------------
// K2: fused attention per batch element (fp32 inputs, bf16 internal).
//   kv = [x_ctx | sin(z) | cos(z)], z = log1p(max(t,0))*freq+phase
//   attT[l][h] = MFMA(kv_lc, qkvec-rows)          (K=256)
//   softmax over l (shuffle), P -> pbuf (A-layout)
//   ctx[h][c]  = MFMA(pbuf, kv_cl)                (K=32)
//   ctx row b OVERWRITES qkvec row b (safe: row fully consumed pre-barrier).
__global__ __launch_bounds__(256) void k2_attn(
    const float* __restrict__ x_ctx, const float* __restrict__ t_ctx,
    const float* __restrict__ freq, const float* __restrict__ phase,
    u16* __restrict__ qkv)
{
    __shared__ __align__(16) u16 kv_lc[32][264];   // [l][c], c-contiguous
    __shared__ __align__(16) u16 kv_cl[256][40];   // [c][l], l-contiguous
    __shared__ __align__(16) u16 pbuf[16][32];     // P in A-layout, rows 4..15 = 0
    __shared__ float attbuf[32][5];
    __shared__ float lt[32];
    __shared__ float fr[64], ph[64];

    const int b = blockIdx.x;
    const int t = threadIdx.x;
    const int lane = t & 63, wave = t >> 6;
    const int quad = lane >> 4, l16 = lane & 15;

    if (t < 64) { fr[t] = freq[t]; ph[t] = phase[t]; }
    else if (t < 96) {
        int l = t - 64;
        lt[l] = log1pf(fmaxf(t_ctx[(size_t)b * 32 + l], 0.f));
    }
    ((u16*)pbuf)[t] = 0; ((u16*)pbuf)[t + 256] = 0;
    __syncthreads();

    if (t < 128) {
        // waves 0,1: convert x_ctx into both kv layouts (c = 0..127)
        #pragma unroll
        for (int i = 0; i < 4; ++i) {
            int idx = t + i * 128;                  // 512 groups of 8 floats
            int row = idx >> 4, ch = idx & 15;
            const float* src = x_ctx + (size_t)(b * 32 + row) * 128 + ch * 8;
            f32x4 a = *(const f32x4*)src;
            f32x4 bb = *(const f32x4*)(src + 4);
            bf16x8 vv = cvt8(a, bb);
            *(bf16x8*)&kv_lc[row][ch * 8] = vv;
            #pragma unroll
            for (int j = 0; j < 8; ++j)
                kv_cl[ch * 8 + j][row] = (u16)vv[j];
        }
    } else {
        // waves 2,3: time encoding (c = 128..255)
        int cc = t - 128;
        int f = cc & 63;
        float frq = fr[f], phs = ph[f];
        bool iscos = cc >= 64;
        for (int l = 0; l < 32; ++l) {
            float z = lt[l] * frq + phs;
            float v = iscos ? __cosf(z) : __sinf(z);
            u16 bv = f2b(v);
            kv_lc[l][128 + cc] = bv;
            kv_cl[128 + cc][l] = bv;
        }
    }
    __syncthreads();

    // attT MFMA: D[l][h]; waves 0,1 take l-tiles 0,1.  B-frag straight from global.
    if (wave < 2) {
        f32x4 aacc = {0.f, 0.f, 0.f, 0.f};
        const u16* qb = qkv + (size_t)b * 1024 + (size_t)(l16 & 3) * 256;
        #pragma unroll
        for (int ks = 0; ks < 8; ++ks) {
            bf16x8 afr = *(const bf16x8*)&kv_lc[wave * 16 + l16][ks * 32 + quad * 8];
            bf16x8 bfr = *(const bf16x8*)(qb + ks * 32 + quad * 8);
            aacc = MFMA16(afr, bfr, aacc);
        }
        if (l16 < 4) {
            #pragma unroll
            for (int r = 0; r < 4; ++r)
                attbuf[wave * 16 + quad * 4 + r][l16] = aacc[r];
        }
    }
    __syncthreads();

    // softmax over l per head; write P as bf16 in MFMA-A layout
    if (t < 128) {
        int h = t >> 5, l = t & 31;
        float a = attbuf[l][h];
        float m = a;
        #pragma unroll
        for (int s = 16; s > 0; s >>= 1) m = fmaxf(m, __shfl_xor(m, s));
        float p = __expf(a - m);
        float sum = p;
        #pragma unroll
        for (int s = 16; s > 0; s >>= 1) sum += __shfl_xor(sum, s);
        pbuf[h][l] = f2b(p / sum);
    }
    __syncthreads();

    // ctx MFMA: D[h][c]; wave w covers c cols w*64..w*64+63 (K=32, 1 step)
    {
        bf16x8 afr = *(const bf16x8*)&pbuf[l16][quad * 8];
        f32x4 zz = {0.f, 0.f, 0.f, 0.f};
        f32x4 cacc[4];
        #pragma unroll
        for (int nt = 0; nt < 4; ++nt) {
            bf16x8 bfr = *(const bf16x8*)&kv_cl[wave * 64 + nt * 16 + l16][quad * 8];
            cacc[nt] = MFMA16(afr, bfr, zz);
        }
        if (quad == 0) {
            #pragma unroll
            for (int nt = 0; nt < 4; ++nt) {
                int col = wave * 64 + nt * 16 + l16;
                #pragma unroll
                for (int r = 0; r < 4; ++r)
                    qkv[(size_t)b * 1024 + r * 256 + col] = f2b(cacc[nt][r]);
            }
        }
    }
}

// ---------------------------------------------------------------------------
// K3: epilogue chain, 16 rows/block, full N=256 in-block (wave w owns cols w*64..).
//   agg = ctx_head @ Wv + xu @ Wres + bres ; z1 = LN1 ; h1 = relu(z1@W1+b1)
//   o = h1@W2 + b2 + z1 ; out = LN2 (fp32 out).  LDS regions aliased.
__global__ __launch_bounds__(256) void k3_epilogue(
    const u16* __restrict__ ctxb, const float* __restrict__ xu,
    const u16* __restrict__ WvT, const u16* __restrict__ WresT,
    const u16* __restrict__ W1T, const u16* __restrict__ W2T,
    const float* __restrict__ bres, const float* __restrict__ b1,
    const float* __restrict__ b2, const float* __restrict__ g1,
    const float* __restrict__ be1, const float* __restrict__ g2,
    const float* __restrict__ be2, float* __restrict__ out)
{
    __shared__ __align__(16) char smem[39552];
    u16  (*ctxs)[1032] = reinterpret_cast<u16 (*)[1032]>(smem);          // [0,33024)
    u16  (*xus)[136]   = reinterpret_cast<u16 (*)[136]>(smem + 33024);   // [33024,37376)
    float(*zbuf)[264]  = reinterpret_cast<float (*)[264]>(smem);         // [0,16896)  (after phase A)
    u16  (*z1b)[264]   = reinterpret_cast<u16 (*)[264]>(smem + 16896);
    u16  (*h1b)[264]   = reinterpret_cast<u16 (*)[264]>(smem + 25344);
    float(*obuf)[264]  = reinterpret_cast<float (*)[264]>(smem + 16896); // overlays z1b+h1b
    float(*red)[16][2] = reinterpret_cast<float (*)[16][2]>(smem + 37376);
    float(*mrstd)[2]   = reinterpret_cast<float (*)[2]>(smem + 39424);

    const int b0 = blockIdx.x * 16;
    const int t = threadIdx.x;
    const int lane = t & 63, wave = t >> 6;
    const int quad = lane >> 4, l16 = lane & 15;
    const int nw = wave * 64;

    #pragma unroll
    for (int i = 0; i < 8; ++i) {
        int idx = t + i * 256;                     // 2048 x 16B chunks (bf16 ctx)
        int row = idx >> 7, ch = idx & 127;
        *(bf16x8*)&ctxs[row][ch * 8] = *(const bf16x8*)(ctxb + (size_t)(b0 + row) * 1024 + ch * 8);
    }
    {
        int row = t >> 4, ch = t & 15;             // 256 groups of 8 floats (x_u)
        const float* src = xu + (size_t)(b0 + row) * 128 + ch * 8;
        f32x4 a = *(const f32x4*)src;
        f32x4 b = *(const f32x4*)(src + 4);
        *(bf16x8*)&xus[row][ch * 8] = cvt8(a, b);
    }
    __syncthreads();

    f32x4 zz = {0.f, 0.f, 0.f, 0.f};

    // ---- Phase A ----
    f32x4 acc[4];
    #pragma unroll
    for (int nt = 0; nt < 4; ++nt) acc[nt] = zz;
    #pragma unroll
    for (int ks = 0; ks < 8; ++ks) {
        bf16x8 afr = *(const bf16x8*)&ctxs[l16][wave * 256 + ks * 32 + quad * 8];
        #pragma unroll
        for (int nt = 0; nt < 4; ++nt) {
            bf16x8 bfr = *(const bf16x8*)(WvT + (size_t)(nw + nt * 16 + l16) * 256 + ks * 32 + quad * 8);
            acc[nt] = MFMA16(afr, bfr, acc[nt]);
        }
    }
    #pragma unroll
    for (int ks = 0; ks < 4; ++ks) {
        bf16x8 afr = *(const bf16x8*)&xus[l16][ks * 32 + quad * 8];
        #pragma unroll
        for (int nt = 0; nt < 4; ++nt) {
            bf16x8 bfr = *(const bf16x8*)(WresT + (size_t)(nw + nt * 16 + l16) * 128 + ks * 32 + quad * 8);
            acc[nt] = MFMA16(afr, bfr, acc[nt]);
        }
    }
    __syncthreads();                               // ctxs/xus dead
    #pragma unroll
    for (int nt = 0; nt < 4; ++nt) {
        int col = nw + nt * 16 + l16;
        float bb = bres[col];
        #pragma unroll
        for (int r = 0; r < 4; ++r)
            zbuf[quad * 4 + r][col] = acc[nt][r] + bb;
    }
    __syncthreads();

    // ---- LN1 ----
    {
        int row = t >> 4, j = t & 15;
        float s = 0.f, s2 = 0.f;
        #pragma unroll
        for (int i = 0; i < 16; ++i) { float v = zbuf[row][j + 16 * i]; s += v; s2 += v * v; }
        red[row][j][0] = s; red[row][j][1] = s2;
    }
    __syncthreads();
    if (t < 16) {
        float s = 0.f, s2 = 0.f;
        #pragma unroll
        for (int j = 0; j < 16; ++j) { s += red[t][j][0]; s2 += red[t][j][1]; }
        float m = s * (1.f / 256.f);
        float var = s2 * (1.f / 256.f) - m * m;
        mrstd[t][0] = m;
        mrstd[t][1] = rsqrtf(var + 1e-5f);
    }
    __syncthreads();
    {
        float g = g1[t], be = be1[t];
        #pragma unroll
        for (int i = 0; i < 16; ++i) {
            float z = (zbuf[i][t] - mrstd[i][0]) * mrstd[i][1] * g + be;
            zbuf[i][t] = z;                        // keep f32 z1 for residual
            z1b[i][t] = f2b(z);
        }
    }
    __syncthreads();

    // ---- Phase B: FFN1 + relu ----
    f32x4 acc2[4];
    #pragma unroll
    for (int nt = 0; nt < 4; ++nt) acc2[nt] = zz;
    #pragma unroll
    for (int ks = 0; ks < 8; ++ks) {
        bf16x8 afr = *(const bf16x8*)&z1b[l16][ks * 32 + quad * 8];
        #pragma unroll
        for (int nt = 0; nt < 4; ++nt) {
            bf16x8 bfr = *(const bf16x8*)(W1T + (size_t)(nw + nt * 16 + l16) * 256 + ks * 32 + quad * 8);
            acc2[nt] = MFMA16(afr, bfr, acc2[nt]);
        }
    }
    #pragma unroll
    for (int nt = 0; nt < 4; ++nt) {
        int col = nw + nt * 16 + l16;
        float bb = b1[col];
        #pragma unroll
        for (int r = 0; r < 4; ++r)
            h1b[quad * 4 + r][col] = f2b(fmaxf(acc2[nt][r] + bb, 0.f));
    }
    __syncthreads();

    // ---- Phase C: FFN2 + residual ----
    f32x4 acc3[4];
    #pragma unroll
    for (int nt = 0; nt < 4; ++nt) acc3[nt] = zz;
    #pragma unroll
    for (int ks = 0; ks < 8; ++ks) {
        bf16x8 afr = *(const bf16x8*)&h1b[l16][ks * 32 + quad * 8];
        #pragma unroll
        for (int nt = 0; nt < 4; ++nt) {
            bf16x8 bfr = *(const bf16x8*)(W2T + (size_t)(nw + nt * 16 + l16) * 256 + ks * 32 + quad * 8);
            acc3[nt] = MFMA16(afr, bfr, acc3[nt]);
        }
    }
    __syncthreads();                               // z1b/h1b dead
    #pragma unroll
    for (int nt = 0; nt < 4; ++nt) {
        int col = nw + nt * 16 + l16;
        float bb = b2[col];
        #pragma unroll
        for (int r = 0; r < 4; ++r) {
            int row = quad * 4 + r;
            obuf[row][col] = acc3[nt][r] + bb + zbuf[row][col];
        }
    }
    __syncthreads();

    // ---- LN2 + store (fp32) ----
    {
        int row = t >> 4, j = t & 15;
        float s = 0.f, s2 = 0.f;
        #pragma unroll
        for (int i = 0; i < 16; ++i) { float v = obuf[row][j + 16 * i]; s += v; s2 += v * v; }
        red[row][j][0] = s; red[row][j][1] = s2;
    }
    __syncthreads();
    if (t < 16) {
        float s = 0.f, s2 = 0.f;
        #pragma unroll
        for (int j = 0; j < 16; ++j) { s += red[t][j][0]; s2 += red[t][j][1]; }
        float m = s * (1.f / 256.f);
        float var = s2 * (1.f / 256.f) - m * m;
        mrstd[t][0] = m;
        mrstd[t][1] = rsqrtf(var + 1e-5f);
    }
    __syncthreads();
    {
        float g = g2[t], be = be2[t];
        #pragma unroll
        for (int i = 0; i < 16; ++i)
            out[(size_t)(b0 + i) * 256 + t] = (obuf[i][t] - mrstd[i][0]) * mrstd[i][1] * g + be;
    }
}

// ---------------------------------------------------------------------------
extern "C" void kernel_launch(void* const* d_in, const int* in_sizes, int n_in,
                              void* d_out, int out_size, void* d_ws, size_t ws_size,
                              hipStream_t stream)
{
    (void)in_sizes; (void)n_in; (void)out_size; (void)ws_size;
    const float* xu    = (const float*)d_in[0];
    const float* x_ctx = (const float*)d_in[1];
    const float* t_ctx = (const float*)d_in[2];
    const float* freq  = (const float*)d_in[3];
    const float* phase = (const float*)d_in[4];
    const float* Wq    = (const float*)d_in[5];
    const float* Wk    = (const float*)d_in[6];
    const float* Wv    = (const float*)d_in[7];
    const float* Wres  = (const float*)d_in[8];
    const float* bres  = (const float*)d_in[9];
    const float* W1    = (const float*)d_in[10];
    const float* b1    = (const float*)d_in[11];
    const float* W2    = (const float*)d_in[12];
    const float* b2    = (const float*)d_in[13];
    const float* g1    = (const float*)d_in[14];
    const float* be1   = (const float*)d_in[15];
    const float* g2    = (const float*)d_in[16];
    const float* be2   = (const float*)d_in[17];
    float* out = (float*)d_out;

    char* ws = (char*)d_ws;
    u16* qkv   = (u16*)(ws);                    // 16384*1024*2 = 33,554,432 (qkvec, then ctx in-place)
    u16* WcatT = (u16*)(ws + 33554432);         // 262,144
    u16* WresT = (u16*)(ws + 33816576);         // 65,536
    u16* WvT   = (u16*)(ws + 33882112);         // 131,072
    u16* W1T   = (u16*)(ws + 34013184);         // 131,072
    u16* W2T   = (u16*)(ws + 34144256);         // 131,072   (total ~32.7 MiB)

    hipLaunchKernelGGL(k0_prep, dim3(1408), dim3(256), 0, stream,
                       Wq, Wk, Wv, Wres, W1, W2, WcatT, WresT, WvT, W1T, W2T);
    hipLaunchKernelGGL(k1_qkvec, dim3(128, 8), dim3(256), 0, stream,
                       xu, WcatT, qkv);
    hipLaunchKernelGGL(k2_attn, dim3(16384), dim3(256), 0, stream,
                       x_ctx, t_ctx, freq, phase, qkv);
    hipLaunchKernelGGL(k3_epilogue, dim3(1024), dim3(256), 0, stream,
                       qkv, xu, WvT, WresT, W1T, W2T,
                       bres, b1, b2, g1, be1, g2, be2, out);
}

// Round 3
// 502.868 us; speedup vs baseline: 1.0037x; 1.0037x over previous
//
#include <hip/hip_runtime.h>

typedef unsigned short u16;
typedef unsigned int   u32;

using bf16x8 = __attribute__((ext_vector_type(8))) short;
using f32x4  = __attribute__((ext_vector_type(4))) float;

#define MFMA16(A, B, C) __builtin_amdgcn_mfma_f32_16x16x32_bf16((A), (B), (C), 0, 0, 0)

static __device__ __forceinline__ u16 f2b(float f) {            // RNE
    u32 u = __builtin_bit_cast(u32, f);
    u32 r = (u + 0x7FFFu + ((u >> 16) & 1u)) >> 16;
    return (u16)r;
}
static __device__ __forceinline__ u16 f2bh(float f) {           // round-half-up
    u32 u = __builtin_bit_cast(u32, f) + 0x8000u;
    return (u16)(u >> 16);
}
// pack two floats -> two bf16 (half-up), a -> low16
static __device__ __forceinline__ u32 pk2(float fa, float fb) {
    u32 a = __builtin_bit_cast(u32, fa) + 0x8000u;
    u32 b = __builtin_bit_cast(u32, fb) + 0x8000u;
    return __builtin_amdgcn_perm(b, a, 0x07060302u);
}
static __device__ __forceinline__ bf16x8 cvt8f(f32x4 a, f32x4 b) {  // fast path
    union { u32 w[4]; bf16x8 v; } r;
    r.w[0] = pk2(a[0], a[1]); r.w[1] = pk2(a[2], a[3]);
    r.w[2] = pk2(b[0], b[1]); r.w[3] = pk2(b[2], b[3]);
    return r.v;
}
static __device__ __forceinline__ bf16x8 cvt8(f32x4 a, f32x4 b) {   // RNE path
    bf16x8 r;
    r[0] = (short)f2b(a[0]); r[1] = (short)f2b(a[1]);
    r[2] = (short)f2b(a[2]); r[3] = (short)f2b(a[3]);
    r[4] = (short)f2b(b[0]); r[5] = (short)f2b(b[1]);
    r[6] = (short)f2b(b[2]); r[7] = (short)f2b(b[3]);
    return r;
}

// ---------------------------------------------------------------------------
// K0: weight prep (fp32 in -> bf16 out).
__global__ __launch_bounds__(256) void k0_prep(
    const float* __restrict__ Wq, const float* __restrict__ Wk,
    const float* __restrict__ Wv, const float* __restrict__ Wres,
    const float* __restrict__ W1, const float* __restrict__ W2,
    u16* __restrict__ WcatT, u16* __restrict__ WresT,
    u16* __restrict__ WvT, u16* __restrict__ W1T, u16* __restrict__ W2T)
{
    int t = blockIdx.x * 256 + threadIdx.x;
    if (t < 131072) {
        int n = t >> 7, i = t & 127;
        int h = n >> 8, c = n & 255;
        const float* wq = Wq + i * 256 + h * 64;
        const float* wk = Wk + c * 256 + h * 64;
        float acc = 0.f;
        #pragma unroll 8
        for (int d = 0; d < 64; ++d) acc += wq[d] * wk[d];
        WcatT[t] = f2b(acc * 0.125f);            // softmax 1/sqrt(64) folded in
    } else if (t < 163840) {
        int o = t - 131072; int n = o >> 7, i = o & 127;
        WresT[o] = f2b(Wres[i * 256 + n]);
    } else if (t < 229376) {
        int o = t - 163840; int n = o >> 8, c = o & 255;
        WvT[o] = f2b(Wv[c * 256 + n]);
    } else if (t < 294912) {
        int o = t - 229376; int n = o >> 8, c = o & 255;
        W1T[o] = f2b(W1[c * 256 + n]);
    } else {
        int o = t - 294912; int n = o >> 8, c = o & 255;
        W2T[o] = f2b(W2[c * 256 + n]);
    }
}

// ---------------------------------------------------------------------------
// K1: qkvec[16384,1024] = x_u[16384,128] @ Wcat[128,1024]   (bf16 MFMA, K=128)
__global__ __launch_bounds__(256) void k1_qkvec(
    const float* __restrict__ xu, const u16* __restrict__ WcatT,
    u16* __restrict__ qkvec)
{
    __shared__ __align__(16) u16 As[128][136];
    const int m0 = blockIdx.x * 128, n0 = blockIdx.y * 128;
    const int t = threadIdx.x;
    #pragma unroll
    for (int i = 0; i < 8; ++i) {
        int c = t + i * 256;
        int row = c >> 4, ch = c & 15;
        const float* src = xu + (size_t)(m0 + row) * 128 + ch * 8;
        f32x4 a = *(const f32x4*)src;
        f32x4 b = *(const f32x4*)(src + 4);
        *(bf16x8*)&As[row][ch * 8] = cvt8(a, b);
    }
    __syncthreads();
    const int lane = t & 63, wave = t >> 6;
    const int quad = lane >> 4, l16 = lane & 15;
    const int mh = (wave >> 1) * 64, nh = (wave & 1) * 64;
    f32x4 zz = {0.f, 0.f, 0.f, 0.f};
    f32x4 acc[4][4];
    #pragma unroll
    for (int mt = 0; mt < 4; ++mt)
        #pragma unroll
        for (int nt = 0; nt < 4; ++nt) acc[mt][nt] = zz;
    #pragma unroll
    for (int ks = 0; ks < 4; ++ks) {
        bf16x8 a[4], b[4];
        #pragma unroll
        for (int mt = 0; mt < 4; ++mt)
            a[mt] = *(const bf16x8*)&As[mh + mt * 16 + l16][ks * 32 + quad * 8];
        #pragma unroll
        for (int nt = 0; nt < 4; ++nt)
            b[nt] = *(const bf16x8*)(WcatT + (size_t)(n0 + nh + nt * 16 + l16) * 128 + ks * 32 + quad * 8);
        #pragma unroll
        for (int mt = 0; mt < 4; ++mt)
            #pragma unroll
            for (int nt = 0; nt < 4; ++nt)
                acc[mt][nt] = MFMA16(a[mt], b[nt], acc[mt][nt]);
    }
    #pragma unroll
    for (int mt = 0; mt < 4; ++mt)
        #pragma unroll
        for (int nt = 0; nt < 4; ++nt) {
            int col = n0 + nh + nt * 16 + l16;
            #pragma unroll
            for (int r = 0; r < 4; ++r) {
                int row = m0 + mh + mt * 16 + quad * 4 + r;
                qkvec[(size_t)row * 1024 + col] = f2b(acc[mt][nt][r]);
            }
        }
}

// ---------------------------------------------------------------------------
// K2 (redesigned): one WAVE per batch element, no shared kv LDS, 1 barrier.
//   attT: A-frags straight from global x_ctx (+ on-the-fly sin/cos te),
//         B-frags = qkvec row b (head-replicated cols).
//   softmax: pure shuffle across quads.
//   ctx:  P redistributed through 256 B/wave LDS; B-frags re-read x_ctx
//         (L1/L2-hot) / recompute te in B-layout. D overwrites qkv row b.
__global__ __launch_bounds__(256) void k2_attn(
    const float* __restrict__ x_ctx, const float* __restrict__ t_ctx,
    const float* __restrict__ freq, const float* __restrict__ phase,
    u16* __restrict__ qkv)
{
    __shared__ __align__(16) u16 pw[4][4][32];     // [wave][h][l]
    const int t = threadIdx.x;
    const int lane = t & 63, wave = t >> 6;
    const int quad = lane >> 4, l16 = lane & 15;
    const int b = blockIdx.x * 4 + wave;
    const int fb = quad * 8;
    const f32x4 zz = {0.f, 0.f, 0.f, 0.f};

    // lt[l] in lanes (0..31 hold l=lane, 32..63 duplicates)
    float ltv = log1pf(fmaxf(t_ctx[(size_t)b * 32 + (lane & 31)], 0.f));

    // freq/phase slices for this quad (L1-hot)
    f32x4 fr0a = *(const f32x4*)(freq + fb);
    f32x4 fr0b = *(const f32x4*)(freq + fb + 4);
    f32x4 fr1a = *(const f32x4*)(freq + 32 + fb);
    f32x4 fr1b = *(const f32x4*)(freq + 32 + fb + 4);
    f32x4 ph0a = *(const f32x4*)(phase + fb);
    f32x4 ph0b = *(const f32x4*)(phase + fb + 4);
    f32x4 ph1a = *(const f32x4*)(phase + 32 + fb);
    f32x4 ph1b = *(const f32x4*)(phase + 32 + fb + 4);

    const u16* qb = qkv + (size_t)b * 1024 + (size_t)(l16 & 3) * 256;

    // ---- attT: D[l][h-replica], K = 256 ----
    f32x4 accA[2];
    #pragma unroll
    for (int ltile = 0; ltile < 2; ++ltile) {
        const int l = ltile * 16 + l16;
        const float* xrow = x_ctx + ((size_t)b * 32 + l) * 128;
        f32x4 acc = zz;
        #pragma unroll
        for (int ks = 0; ks < 4; ++ks) {
            f32x4 a = *(const f32x4*)(xrow + ks * 32 + fb);
            f32x4 c = *(const f32x4*)(xrow + ks * 32 + fb + 4);
            bf16x8 afr = cvt8f(a, c);
            bf16x8 bfr = *(const bf16x8*)(qb + ks * 32 + fb);
            acc = MFMA16(afr, bfr, acc);
        }
        float lt_l = __shfl(ltv, l);
        f32x4 z0a = fr0a * lt_l + ph0a;
        f32x4 z0b = fr0b * lt_l + ph0b;
        f32x4 z1a = fr1a * lt_l + ph1a;
        f32x4 z1b = fr1b * lt_l + ph1b;
        f32x4 s0a, s0b, s1a, s1b, c0a, c0b, c1a, c1b;
        #pragma unroll
        for (int j = 0; j < 4; ++j) {
            s0a[j] = __sinf(z0a[j]); s0b[j] = __sinf(z0b[j]);
            s1a[j] = __sinf(z1a[j]); s1b[j] = __sinf(z1b[j]);
            c0a[j] = __cosf(z0a[j]); c0b[j] = __cosf(z0b[j]);
            c1a[j] = __cosf(z1a[j]); c1b[j] = __cosf(z1b[j]);
        }
        acc = MFMA16(cvt8f(s0a, s0b), *(const bf16x8*)(qb + 128 + fb), acc);
        acc = MFMA16(cvt8f(s1a, s1b), *(const bf16x8*)(qb + 160 + fb), acc);
        acc = MFMA16(cvt8f(c0a, c0b), *(const bf16x8*)(qb + 192 + fb), acc);
        acc = MFMA16(cvt8f(c1a, c1b), *(const bf16x8*)(qb + 224 + fb), acc);
        accA[ltile] = acc;
    }

    // ---- softmax over l (8 per lane + xor16/xor32 across quads) ----
    float m = accA[0][0];
    #pragma unroll
    for (int r = 1; r < 4; ++r) m = fmaxf(m, accA[0][r]);
    #pragma unroll
    for (int r = 0; r < 4; ++r) m = fmaxf(m, accA[1][r]);
    m = fmaxf(m, __shfl_xor(m, 16));
    m = fmaxf(m, __shfl_xor(m, 32));
    float p[2][4], s = 0.f;
    #pragma unroll
    for (int lt2 = 0; lt2 < 2; ++lt2)
        #pragma unroll
        for (int r = 0; r < 4; ++r) { p[lt2][r] = __expf(accA[lt2][r] - m); s += p[lt2][r]; }
    s += __shfl_xor(s, 16);
    s += __shfl_xor(s, 32);
    float inv = 1.f / s;
    if (l16 < 4) {
        #pragma unroll
        for (int lt2 = 0; lt2 < 2; ++lt2)
            #pragma unroll
            for (int r = 0; r < 4; ++r)
                pw[wave][l16][lt2 * 16 + quad * 4 + r] = f2bh(p[lt2][r] * inv);
    }
    __syncthreads();

    // ---- ctx: D[h][c] = P @ KV, K = 32 (one MFMA per 16-col tile) ----
    bf16x8 pfr = *(const bf16x8*)&pw[wave][l16 & 3][fb];   // A[m=h][k=l]
    float ltj[8];
    #pragma unroll
    for (int j = 0; j < 8; ++j) ltj[j] = __shfl(ltv, fb + j);

    u16* crow = qkv + (size_t)b * 1024;
    // c < 128: B from x_ctx (strided scalar, L1/L2-hot)
    #pragma unroll
    for (int nt = 0; nt < 8; ++nt) {
        int c = nt * 16 + l16;
        const float* xp = x_ctx + ((size_t)b * 32 + fb) * 128 + c;
        float v0 = xp[0], v1 = xp[128], v2 = xp[256], v3 = xp[384];
        float v4 = xp[512], v5 = xp[640], v6 = xp[768], v7 = xp[896];
        union { u32 w[4]; bf16x8 v; } bu;
        bu.w[0] = pk2(v0, v1); bu.w[1] = pk2(v2, v3);
        bu.w[2] = pk2(v4, v5); bu.w[3] = pk2(v6, v7);
        f32x4 d = MFMA16(pfr, bu.v, zz);
        if (quad == 0) {
            #pragma unroll
            for (int r = 0; r < 4; ++r) crow[r * 256 + c] = f2bh(d[r]);
        }
    }
    // c >= 128: te in B-layout (lane = fixed f, k = 8 consecutive l)
    #pragma unroll
    for (int pp = 0; pp < 4; ++pp) {
        int f = pp * 16 + l16;
        float fq = freq[f], phf = phase[f];
        float z8[8];
        #pragma unroll
        for (int j = 0; j < 8; ++j) z8[j] = ltj[j] * fq + phf;
        union { u32 w[4]; bf16x8 v; } bs, bc;
        #pragma unroll
        for (int j = 0; j < 4; ++j) {
            bs.w[j] = pk2(__sinf(z8[2 * j]), __sinf(z8[2 * j + 1]));
            bc.w[j] = pk2(__cosf(z8[2 * j]), __cosf(z8[2 * j + 1]));
        }
        f32x4 ds = MFMA16(pfr, bs.v, zz);
        f32x4 dc = MFMA16(pfr, bc.v, zz);
        if (quad == 0) {
            #pragma unroll
            for (int r = 0; r < 4; ++r) {
                crow[r * 256 + 128 + f] = f2bh(ds[r]);
                crow[r * 256 + 192 + f] = f2bh(dc[r]);
            }
        }
    }
}

// ---------------------------------------------------------------------------
// K3: epilogue chain, 16 rows/block (unchanged from round 2).
__global__ __launch_bounds__(256) void k3_epilogue(
    const u16* __restrict__ ctxb, const float* __restrict__ xu,
    const u16* __restrict__ WvT, const u16* __restrict__ WresT,
    const u16* __restrict__ W1T, const u16* __restrict__ W2T,
    const float* __restrict__ bres, const float* __restrict__ b1,
    const float* __restrict__ b2, const float* __restrict__ g1,
    const float* __restrict__ be1, const float* __restrict__ g2,
    const float* __restrict__ be2, float* __restrict__ out)
{
    __shared__ __align__(16) char smem[39552];
    u16  (*ctxs)[1032] = reinterpret_cast<u16 (*)[1032]>(smem);
    u16  (*xus)[136]   = reinterpret_cast<u16 (*)[136]>(smem + 33024);
    float(*zbuf)[264]  = reinterpret_cast<float (*)[264]>(smem);
    u16  (*z1b)[264]   = reinterpret_cast<u16 (*)[264]>(smem + 16896);
    u16  (*h1b)[264]   = reinterpret_cast<u16 (*)[264]>(smem + 25344);
    float(*obuf)[264]  = reinterpret_cast<float (*)[264]>(smem + 16896);
    float(*red)[16][2] = reinterpret_cast<float (*)[16][2]>(smem + 37376);
    float(*mrstd)[2]   = reinterpret_cast<float (*)[2]>(smem + 39424);

    const int b0 = blockIdx.x * 16;
    const int t = threadIdx.x;
    const int lane = t & 63, wave = t >> 6;
    const int quad = lane >> 4, l16 = lane & 15;
    const int nw = wave * 64;

    #pragma unroll
    for (int i = 0; i < 8; ++i) {
        int idx = t + i * 256;
        int row = idx >> 7, ch = idx & 127;
        *(bf16x8*)&ctxs[row][ch * 8] = *(const bf16x8*)(ctxb + (size_t)(b0 + row) * 1024 + ch * 8);
    }
    {
        int row = t >> 4, ch = t & 15;
        const float* src = xu + (size_t)(b0 + row) * 128 + ch * 8;
        f32x4 a = *(const f32x4*)src;
        f32x4 b = *(const f32x4*)(src + 4);
        *(bf16x8*)&xus[row][ch * 8] = cvt8(a, b);
    }
    __syncthreads();

    f32x4 zz = {0.f, 0.f, 0.f, 0.f};

    // ---- Phase A ----
    f32x4 acc[4];
    #pragma unroll
    for (int nt = 0; nt < 4; ++nt) acc[nt] = zz;
    #pragma unroll
    for (int ks = 0; ks < 8; ++ks) {
        bf16x8 afr = *(const bf16x8*)&ctxs[l16][wave * 256 + ks * 32 + quad * 8];
        #pragma unroll
        for (int nt = 0; nt < 4; ++nt) {
            bf16x8 bfr = *(const bf16x8*)(WvT + (size_t)(nw + nt * 16 + l16) * 256 + ks * 32 + quad * 8);
            acc[nt] = MFMA16(afr, bfr, acc[nt]);
        }
    }
    #pragma unroll
    for (int ks = 0; ks < 4; ++ks) {
        bf16x8 afr = *(const bf16x8*)&xus[l16][ks * 32 + quad * 8];
        #pragma unroll
        for (int nt = 0; nt < 4; ++nt) {
            bf16x8 bfr = *(const bf16x8*)(WresT + (size_t)(nw + nt * 16 + l16) * 128 + ks * 32 + quad * 8);
            acc[nt] = MFMA16(afr, bfr, acc[nt]);
        }
    }
    __syncthreads();
    #pragma unroll
    for (int nt = 0; nt < 4; ++nt) {
        int col = nw + nt * 16 + l16;
        float bb = bres[col];
        #pragma unroll
        for (int r = 0; r < 4; ++r)
            zbuf[quad * 4 + r][col] = acc[nt][r] + bb;
    }
    __syncthreads();

    // ---- LN1 ----
    {
        int row = t >> 4, j = t & 15;
        float s = 0.f, s2 = 0.f;
        #pragma unroll
        for (int i = 0; i < 16; ++i) { float v = zbuf[row][j + 16 * i]; s += v; s2 += v * v; }
        red[row][j][0] = s; red[row][j][1] = s2;
    }
    __syncthreads();
    if (t < 16) {
        float s = 0.f, s2 = 0.f;
        #pragma unroll
        for (int j = 0; j < 16; ++j) { s += red[t][j][0]; s2 += red[t][j][1]; }
        float m = s * (1.f / 256.f);
        float var = s2 * (1.f / 256.f) - m * m;
        mrstd[t][0] = m;
        mrstd[t][1] = rsqrtf(var + 1e-5f);
    }
    __syncthreads();
    {
        float g = g1[t], be = be1[t];
        #pragma unroll
        for (int i = 0; i < 16; ++i) {
            float z = (zbuf[i][t] - mrstd[i][0]) * mrstd[i][1] * g + be;
            zbuf[i][t] = z;
            z1b[i][t] = f2b(z);
        }
    }
    __syncthreads();

    // ---- Phase B: FFN1 + relu ----
    f32x4 acc2[4];
    #pragma unroll
    for (int nt = 0; nt < 4; ++nt) acc2[nt] = zz;
    #pragma unroll
    for (int ks = 0; ks < 8; ++ks) {
        bf16x8 afr = *(const bf16x8*)&z1b[l16][ks * 32 + quad * 8];
        #pragma unroll
        for (int nt = 0; nt < 4; ++nt) {
            bf16x8 bfr = *(const bf16x8*)(W1T + (size_t)(nw + nt * 16 + l16) * 256 + ks * 32 + quad * 8);
            acc2[nt] = MFMA16(afr, bfr, acc2[nt]);
        }
    }
    #pragma unroll
    for (int nt = 0; nt < 4; ++nt) {
        int col = nw + nt * 16 + l16;
        float bb = b1[col];
        #pragma unroll
        for (int r = 0; r < 4; ++r)
            h1b[quad * 4 + r][col] = f2b(fmaxf(acc2[nt][r] + bb, 0.f));
    }
    __syncthreads();

    // ---- Phase C: FFN2 + residual ----
    f32x4 acc3[4];
    #pragma unroll
    for (int nt = 0; nt < 4; ++nt) acc3[nt] = zz;
    #pragma unroll
    for (int ks = 0; ks < 8; ++ks) {
        bf16x8 afr = *(const bf16x8*)&h1b[l16][ks * 32 + quad * 8];
        #pragma unroll
        for (int nt = 0; nt < 4; ++nt) {
            bf16x8 bfr = *(const bf16x8*)(W2T + (size_t)(nw + nt * 16 + l16) * 256 + ks * 32 + quad * 8);
            acc3[nt] = MFMA16(afr, bfr, acc3[nt]);
        }
    }
    __syncthreads();
    #pragma unroll
    for (int nt = 0; nt < 4; ++nt) {
        int col = nw + nt * 16 + l16;
        float bb = b2[col];
        #pragma unroll
        for (int r = 0; r < 4; ++r) {
            int row = quad * 4 + r;
            obuf[row][col] = acc3[nt][r] + bb + zbuf[row][col];
        }
    }
    __syncthreads();

    // ---- LN2 + store (fp32) ----
    {
        int row = t >> 4, j = t & 15;
        float s = 0.f, s2 = 0.f;
        #pragma unroll
        for (int i = 0; i < 16; ++i) { float v = obuf[row][j + 16 * i]; s += v; s2 += v * v; }
        red[row][j][0] = s; red[row][j][1] = s2;
    }
    __syncthreads();
    if (t < 16) {
        float s = 0.f, s2 = 0.f;
        #pragma unroll
        for (int j = 0; j < 16; ++j) { s += red[t][j][0]; s2 += red[t][j][1]; }
        float m = s * (1.f / 256.f);
        float var = s2 * (1.f / 256.f) - m * m;
        mrstd[t][0] = m;
        mrstd[t][1] = rsqrtf(var + 1e-5f);
    }
    __syncthreads();
    {
        float g = g2[t], be = be2[t];
        #pragma unroll
        for (int i = 0; i < 16; ++i)
            out[(size_t)(b0 + i) * 256 + t] = (obuf[i][t] - mrstd[i][0]) * mrstd[i][1] * g + be;
    }
}

// ---------------------------------------------------------------------------
extern "C" void kernel_launch(void* const* d_in, const int* in_sizes, int n_in,
                              void* d_out, int out_size, void* d_ws, size_t ws_size,
                              hipStream_t stream)
{
    (void)in_sizes; (void)n_in; (void)out_size; (void)ws_size;
    const float* xu    = (const float*)d_in[0];
    const float* x_ctx = (const float*)d_in[1];
    const float* t_ctx = (const float*)d_in[2];
    const float* freq  = (const float*)d_in[3];
    const float* phase = (const float*)d_in[4];
    const float* Wq    = (const float*)d_in[5];
    const float* Wk    = (const float*)d_in[6];
    const float* Wv    = (const float*)d_in[7];
    const float* Wres  = (const float*)d_in[8];
    const float* bres  = (const float*)d_in[9];
    const float* W1    = (const float*)d_in[10];
    const float* b1    = (const float*)d_in[11];
    const float* W2    = (const float*)d_in[12];
    const float* b2    = (const float*)d_in[13];
    const float* g1    = (const float*)d_in[14];
    const float* be1   = (const float*)d_in[15];
    const float* g2    = (const float*)d_in[16];
    const float* be2   = (const float*)d_in[17];
    float* out = (float*)d_out;

    char* ws = (char*)d_ws;
    u16* qkv   = (u16*)(ws);                    // 33,554,432 B (qkvec, then ctx in-place)
    u16* WcatT = (u16*)(ws + 33554432);
    u16* WresT = (u16*)(ws + 33816576);
    u16* WvT   = (u16*)(ws + 33882112);
    u16* W1T   = (u16*)(ws + 34013184);
    u16* W2T   = (u16*)(ws + 34144256);

    hipLaunchKernelGGL(k0_prep, dim3(1408), dim3(256), 0, stream,
                       Wq, Wk, Wv, Wres, W1, W2, WcatT, WresT, WvT, W1T, W2T);
    hipLaunchKernelGGL(k1_qkvec, dim3(128, 8), dim3(256), 0, stream,
                       xu, WcatT, qkv);
    hipLaunchKernelGGL(k2_attn, dim3(4096), dim3(256), 0, stream,
                       x_ctx, t_ctx, freq, phase, qkv);
    hipLaunchKernelGGL(k3_epilogue, dim3(1024), dim3(256), 0, stream,
                       qkv, xu, WvT, WresT, W1T, W2T,
                       bres, b1, b2, g1, be1, g2, be2, out);
}

// Round 4
// 501.044 us; speedup vs baseline: 1.0074x; 1.0036x over previous
//
#include <hip/hip_runtime.h>

typedef unsigned short u16;
typedef unsigned int   u32;

using bf16x8 = __attribute__((ext_vector_type(8))) short;
using f32x4  = __attribute__((ext_vector_type(4))) float;

#define MFMA16(A, B, C) __builtin_amdgcn_mfma_f32_16x16x32_bf16((A), (B), (C), 0, 0, 0)

static __device__ __forceinline__ u16 f2b(float f) {            // RNE
    u32 u = __builtin_bit_cast(u32, f);
    u32 r = (u + 0x7FFFu + ((u >> 16) & 1u)) >> 16;
    return (u16)r;
}
static __device__ __forceinline__ u16 f2bh(float f) {           // round-half-up
    u32 u = __builtin_bit_cast(u32, f) + 0x8000u;
    return (u16)(u >> 16);
}
// pack two floats -> two bf16 (half-up), a -> low16
static __device__ __forceinline__ u32 pk2(float fa, float fb) {
    u32 a = __builtin_bit_cast(u32, fa) + 0x8000u;
    u32 b = __builtin_bit_cast(u32, fb) + 0x8000u;
    return __builtin_amdgcn_perm(b, a, 0x07060302u);
}
static __device__ __forceinline__ bf16x8 cvt8f(f32x4 a, f32x4 b) {
    union { u32 w[4]; bf16x8 v; } r;
    r.w[0] = pk2(a[0], a[1]); r.w[1] = pk2(a[2], a[3]);
    r.w[2] = pk2(b[0], b[1]); r.w[3] = pk2(b[2], b[3]);
    return r.v;
}
static __device__ __forceinline__ bf16x8 cvt8(f32x4 a, f32x4 b) {   // RNE
    bf16x8 r;
    r[0] = (short)f2b(a[0]); r[1] = (short)f2b(a[1]);
    r[2] = (short)f2b(a[2]); r[3] = (short)f2b(a[3]);
    r[4] = (short)f2b(b[0]); r[5] = (short)f2b(b[1]);
    r[6] = (short)f2b(b[2]); r[7] = (short)f2b(b[3]);
    return r;
}

// ---------------------------------------------------------------------------
// K0: weight prep (fp32 -> bf16), unchanged.
__global__ __launch_bounds__(256) void k0_prep(
    const float* __restrict__ Wq, const float* __restrict__ Wk,
    const float* __restrict__ Wv, const float* __restrict__ Wres,
    const float* __restrict__ W1, const float* __restrict__ W2,
    u16* __restrict__ WcatT, u16* __restrict__ WresT,
    u16* __restrict__ WvT, u16* __restrict__ W1T, u16* __restrict__ W2T)
{
    int t = blockIdx.x * 256 + threadIdx.x;
    if (t < 131072) {
        int n = t >> 7, i = t & 127;
        int h = n >> 8, c = n & 255;
        const float* wq = Wq + i * 256 + h * 64;
        const float* wk = Wk + c * 256 + h * 64;
        float acc = 0.f;
        #pragma unroll 8
        for (int d = 0; d < 64; ++d) acc += wq[d] * wk[d];
        WcatT[t] = f2b(acc * 0.125f);
    } else if (t < 163840) {
        int o = t - 131072; int n = o >> 7, i = o & 127;
        WresT[o] = f2b(Wres[i * 256 + n]);
    } else if (t < 229376) {
        int o = t - 163840; int n = o >> 8, c = o & 255;
        WvT[o] = f2b(Wv[c * 256 + n]);
    } else if (t < 294912) {
        int o = t - 229376; int n = o >> 8, c = o & 255;
        W1T[o] = f2b(W1[c * 256 + n]);
    } else {
        int o = t - 294912; int n = o >> 8, c = o & 255;
        W2T[o] = f2b(W2[c * 256 + n]);
    }
}

// ---------------------------------------------------------------------------
// KF: fully fused qkvec-GEMM + attention + epilogue. 16 batch rows per block.
//   P1: kv[16][1024] = x_u @ Wcat   (LDS)
//   P2: per wave, 4 b's: attT (A from x_ctx+te, B = kv row via LDS),
//       shuffle softmax, PV -> ctx overwrites kv row in place.
//   P3: K3 epilogue on kv (= ctx) + xus, LDS-aliased phases, fp32 out.
__global__ __launch_bounds__(256, 4) void kf_fused(
    const float* __restrict__ xu, const float* __restrict__ x_ctx,
    const float* __restrict__ t_ctx, const float* __restrict__ freq,
    const float* __restrict__ phase,
    const u16* __restrict__ WcatT, const u16* __restrict__ WvT,
    const u16* __restrict__ WresT, const u16* __restrict__ W1T,
    const u16* __restrict__ W2T,
    const float* __restrict__ bres, const float* __restrict__ b1,
    const float* __restrict__ b2, const float* __restrict__ g1,
    const float* __restrict__ be1, const float* __restrict__ g2,
    const float* __restrict__ be2, float* __restrict__ out)
{
    __shared__ __align__(16) char smem[40576];
    u16  (*kv)[1032]   = reinterpret_cast<u16 (*)[1032]>(smem);          // [0,33024)
    u16  (*xus)[136]   = reinterpret_cast<u16 (*)[136]>(smem + 33024);   // [33024,37376)
    u16  (*pw)[4][32]  = reinterpret_cast<u16 (*)[4][32]>(smem + 37376); // [37376,38400)
    float(*red)[16][2] = reinterpret_cast<float (*)[16][2]>(smem + 38400);
    float(*mrstd)[2]   = reinterpret_cast<float (*)[2]>(smem + 40448);
    float(*zbuf)[264]  = reinterpret_cast<float (*)[264]>(smem);         // alias kv
    u16  (*z1b)[264]   = reinterpret_cast<u16 (*)[264]>(smem + 16896);
    u16  (*h1b)[264]   = reinterpret_cast<u16 (*)[264]>(smem + 25344);   // tail overlaps xus (dead)
    float(*obuf)[264]  = reinterpret_cast<float (*)[264]>(smem + 16896);

    const int b0 = blockIdx.x * 16;
    const int t = threadIdx.x;
    const int lane = t & 63, wave = t >> 6;
    const int quad = lane >> 4, l16 = lane & 15;
    const int fb = quad * 8;
    const int nw = wave * 64;
    const f32x4 zz = {0.f, 0.f, 0.f, 0.f};

    // ---- P0: stage x_u rows (bf16) ----
    {
        int row = t >> 4, ch = t & 15;
        const float* src = xu + (size_t)(b0 + row) * 128 + ch * 8;
        *(bf16x8*)&xus[row][ch * 8] = cvt8(*(const f32x4*)src, *(const f32x4*)(src + 4));
    }
    __syncthreads();

    // ---- P1: kv[row][n] = qkvec = x_u @ Wcat (K=128), wave owns n-range w*256.. ----
    #pragma unroll 4
    for (int nt = 0; nt < 16; ++nt) {
        int n0 = wave * 256 + nt * 16;
        f32x4 acc = zz;
        #pragma unroll
        for (int ks = 0; ks < 4; ++ks) {
            bf16x8 afr = *(const bf16x8*)&xus[l16][ks * 32 + fb];
            bf16x8 bfr = *(const bf16x8*)(WcatT + (size_t)(n0 + l16) * 128 + ks * 32 + fb);
            acc = MFMA16(afr, bfr, acc);
        }
        #pragma unroll
        for (int r = 0; r < 4; ++r)
            kv[quad * 4 + r][n0 + l16] = f2b(acc[r]);
    }
    __syncthreads();

    // ---- P2: attention; wave w handles b = b0 + w*4 + i ----
    f32x4 fr0a = *(const f32x4*)(freq + fb);
    f32x4 fr0b = *(const f32x4*)(freq + fb + 4);
    f32x4 fr1a = *(const f32x4*)(freq + 32 + fb);
    f32x4 fr1b = *(const f32x4*)(freq + 32 + fb + 4);
    f32x4 ph0a = *(const f32x4*)(phase + fb);
    f32x4 ph0b = *(const f32x4*)(phase + fb + 4);
    f32x4 ph1a = *(const f32x4*)(phase + 32 + fb);
    f32x4 ph1b = *(const f32x4*)(phase + 32 + fb + 4);

    for (int i = 0; i < 4; ++i) {
        const int kvrow = wave * 4 + i;
        const int b = b0 + kvrow;
        float ltv = log1pf(fmaxf(t_ctx[(size_t)b * 32 + (lane & 31)], 0.f));
        const u16* qb = &kv[kvrow][(l16 & 3) * 256];

        // attT: D[l][h-replica], K=256
        f32x4 accA[2];
        #pragma unroll
        for (int ltile = 0; ltile < 2; ++ltile) {
            const int l = ltile * 16 + l16;
            const float* xrow = x_ctx + ((size_t)b * 32 + l) * 128;
            f32x4 acc = zz;
            #pragma unroll
            for (int ks = 0; ks < 4; ++ks) {
                f32x4 a = *(const f32x4*)(xrow + ks * 32 + fb);
                f32x4 c = *(const f32x4*)(xrow + ks * 32 + fb + 4);
                acc = MFMA16(cvt8f(a, c), *(const bf16x8*)(qb + ks * 32 + fb), acc);
            }
            float lt_l = __shfl(ltv, l);
            f32x4 z0a = fr0a * lt_l + ph0a;
            f32x4 z0b = fr0b * lt_l + ph0b;
            f32x4 z1a = fr1a * lt_l + ph1a;
            f32x4 z1b_ = fr1b * lt_l + ph1b;
            f32x4 s0a, s0b, s1a, s1b, c0a, c0b, c1a, c1b;
            #pragma unroll
            for (int j = 0; j < 4; ++j) {
                s0a[j] = __sinf(z0a[j]); s0b[j] = __sinf(z0b[j]);
                s1a[j] = __sinf(z1a[j]); s1b[j] = __sinf(z1b_[j]);
                c0a[j] = __cosf(z0a[j]); c0b[j] = __cosf(z0b[j]);
                c1a[j] = __cosf(z1a[j]); c1b[j] = __cosf(z1b_[j]);
            }
            acc = MFMA16(cvt8f(s0a, s0b), *(const bf16x8*)(qb + 128 + fb), acc);
            acc = MFMA16(cvt8f(s1a, s1b), *(const bf16x8*)(qb + 160 + fb), acc);
            acc = MFMA16(cvt8f(c0a, c0b), *(const bf16x8*)(qb + 192 + fb), acc);
            acc = MFMA16(cvt8f(c1a, c1b), *(const bf16x8*)(qb + 224 + fb), acc);
            accA[ltile] = acc;
        }

        // softmax over l
        float m = accA[0][0];
        #pragma unroll
        for (int r = 1; r < 4; ++r) m = fmaxf(m, accA[0][r]);
        #pragma unroll
        for (int r = 0; r < 4; ++r) m = fmaxf(m, accA[1][r]);
        m = fmaxf(m, __shfl_xor(m, 16));
        m = fmaxf(m, __shfl_xor(m, 32));
        float p[2][4], s = 0.f;
        #pragma unroll
        for (int lt2 = 0; lt2 < 2; ++lt2)
            #pragma unroll
            for (int r = 0; r < 4; ++r) { p[lt2][r] = __expf(accA[lt2][r] - m); s += p[lt2][r]; }
        s += __shfl_xor(s, 16);
        s += __shfl_xor(s, 32);
        float inv = 1.f / s;
        if (l16 < 4) {
            #pragma unroll
            for (int lt2 = 0; lt2 < 2; ++lt2)
                #pragma unroll
                for (int r = 0; r < 4; ++r)
                    pw[wave][l16][lt2 * 16 + quad * 4 + r] = f2bh(p[lt2][r] * inv);
        }
        __syncthreads();   // uniform; also orders pw write->read (per-wave data)

        // PV: ctx[h][c] overwrites kv[kvrow] in place (row fully consumed above)
        bf16x8 pfr = *(const bf16x8*)&pw[wave][l16 & 3][fb];
        float ltj[8];
        #pragma unroll
        for (int j = 0; j < 8; ++j) ltj[j] = __shfl(ltv, fb + j);

        #pragma unroll
        for (int nt = 0; nt < 8; ++nt) {
            int c = nt * 16 + l16;
            const float* xp = x_ctx + ((size_t)b * 32 + fb) * 128 + c;
            float v0 = xp[0], v1 = xp[128], v2 = xp[256], v3 = xp[384];
            float v4 = xp[512], v5 = xp[640], v6 = xp[768], v7 = xp[896];
            union { u32 w[4]; bf16x8 v; } bu;
            bu.w[0] = pk2(v0, v1); bu.w[1] = pk2(v2, v3);
            bu.w[2] = pk2(v4, v5); bu.w[3] = pk2(v6, v7);
            f32x4 d = MFMA16(pfr, bu.v, zz);
            if (quad == 0) {
                #pragma unroll
                for (int r = 0; r < 4; ++r) kv[kvrow][r * 256 + c] = f2bh(d[r]);
            }
        }
        #pragma unroll
        for (int pp = 0; pp < 4; ++pp) {
            int f = pp * 16 + l16;
            float fq = freq[f], phf = phase[f];
            float z8[8];
            #pragma unroll
            for (int j = 0; j < 8; ++j) z8[j] = ltj[j] * fq + phf;
            union { u32 w[4]; bf16x8 v; } bs, bc;
            #pragma unroll
            for (int j = 0; j < 4; ++j) {
                bs.w[j] = pk2(__sinf(z8[2 * j]), __sinf(z8[2 * j + 1]));
                bc.w[j] = pk2(__cosf(z8[2 * j]), __cosf(z8[2 * j + 1]));
            }
            f32x4 ds = MFMA16(pfr, bs.v, zz);
            f32x4 dc = MFMA16(pfr, bc.v, zz);
            if (quad == 0) {
                #pragma unroll
                for (int r = 0; r < 4; ++r) {
                    kv[kvrow][r * 256 + 128 + f] = f2bh(ds[r]);
                    kv[kvrow][r * 256 + 192 + f] = f2bh(dc[r]);
                }
            }
        }
    }
    __syncthreads();

    // ---- P3: epilogue (K3 body; ctxs == kv) ----
    // Phase A: agg = ctx_head @ Wv + xu @ Wres + bres
    f32x4 acc[4];
    #pragma unroll
    for (int nt = 0; nt < 4; ++nt) acc[nt] = zz;
    #pragma unroll
    for (int ks = 0; ks < 8; ++ks) {
        bf16x8 afr = *(const bf16x8*)&kv[l16][wave * 256 + ks * 32 + quad * 8];
        #pragma unroll
        for (int nt = 0; nt < 4; ++nt) {
            bf16x8 bfr = *(const bf16x8*)(WvT + (size_t)(nw + nt * 16 + l16) * 256 + ks * 32 + quad * 8);
            acc[nt] = MFMA16(afr, bfr, acc[nt]);
        }
    }
    #pragma unroll
    for (int ks = 0; ks < 4; ++ks) {
        bf16x8 afr = *(const bf16x8*)&xus[l16][ks * 32 + quad * 8];
        #pragma unroll
        for (int nt = 0; nt < 4; ++nt) {
            bf16x8 bfr = *(const bf16x8*)(WresT + (size_t)(nw + nt * 16 + l16) * 128 + ks * 32 + quad * 8);
            acc[nt] = MFMA16(afr, bfr, acc[nt]);
        }
    }
    __syncthreads();                               // kv/xus dead
    #pragma unroll
    for (int nt = 0; nt < 4; ++nt) {
        int col = nw + nt * 16 + l16;
        float bb = bres[col];
        #pragma unroll
        for (int r = 0; r < 4; ++r)
            zbuf[quad * 4 + r][col] = acc[nt][r] + bb;
    }
    __syncthreads();

    // LN1
    {
        int row = t >> 4, j = t & 15;
        float s = 0.f, s2 = 0.f;
        #pragma unroll
        for (int i2 = 0; i2 < 16; ++i2) { float v = zbuf[row][j + 16 * i2]; s += v; s2 += v * v; }
        red[row][j][0] = s; red[row][j][1] = s2;
    }
    __syncthreads();
    if (t < 16) {
        float s = 0.f, s2 = 0.f;
        #pragma unroll
        for (int j = 0; j < 16; ++j) { s += red[t][j][0]; s2 += red[t][j][1]; }
        float m = s * (1.f / 256.f);
        float var = s2 * (1.f / 256.f) - m * m;
        mrstd[t][0] = m;
        mrstd[t][1] = rsqrtf(var + 1e-5f);
    }
    __syncthreads();
    {
        float g = g1[t], be = be1[t];
        #pragma unroll
        for (int i2 = 0; i2 < 16; ++i2) {
            float z = (zbuf[i2][t] - mrstd[i2][0]) * mrstd[i2][1] * g + be;
            zbuf[i2][t] = z;
            z1b[i2][t] = f2b(z);
        }
    }
    __syncthreads();

    // Phase B: FFN1 + relu
    f32x4 acc2[4];
    #pragma unroll
    for (int nt = 0; nt < 4; ++nt) acc2[nt] = zz;
    #pragma unroll
    for (int ks = 0; ks < 8; ++ks) {
        bf16x8 afr = *(const bf16x8*)&z1b[l16][ks * 32 + quad * 8];
        #pragma unroll
        for (int nt = 0; nt < 4; ++nt) {
            bf16x8 bfr = *(const bf16x8*)(W1T + (size_t)(nw + nt * 16 + l16) * 256 + ks * 32 + quad * 8);
            acc2[nt] = MFMA16(afr, bfr, acc2[nt]);
        }
    }
    #pragma unroll
    for (int nt = 0; nt < 4; ++nt) {
        int col = nw + nt * 16 + l16;
        float bb = b1[col];
        #pragma unroll
        for (int r = 0; r < 4; ++r)
            h1b[quad * 4 + r][col] = f2b(fmaxf(acc2[nt][r] + bb, 0.f));
    }
    __syncthreads();

    // Phase C: FFN2 + residual
    f32x4 acc3[4];
    #pragma unroll
    for (int nt = 0; nt < 4; ++nt) acc3[nt] = zz;
    #pragma unroll
    for (int ks = 0; ks < 8; ++ks) {
        bf16x8 afr = *(const bf16x8*)&h1b[l16][ks * 32 + quad * 8];
        #pragma unroll
        for (int nt = 0; nt < 4; ++nt) {
            bf16x8 bfr = *(const bf16x8*)(W2T + (size_t)(nw + nt * 16 + l16) * 256 + ks * 32 + quad * 8);
            acc3[nt] = MFMA16(afr, bfr, acc3[nt]);
        }
    }
    __syncthreads();                               // z1b/h1b dead
    #pragma unroll
    for (int nt = 0; nt < 4; ++nt) {
        int col = nw + nt * 16 + l16;
        float bb = b2[col];
        #pragma unroll
        for (int r = 0; r < 4; ++r) {
            int row = quad * 4 + r;
            obuf[row][col] = acc3[nt][r] + bb + zbuf[row][col];
        }
    }
    __syncthreads();

    // LN2 + store (fp32)
    {
        int row = t >> 4, j = t & 15;
        float s = 0.f, s2 = 0.f;
        #pragma unroll
        for (int i2 = 0; i2 < 16; ++i2) { float v = obuf[row][j + 16 * i2]; s += v; s2 += v * v; }
        red[row][j][0] = s; red[row][j][1] = s2;
    }
    __syncthreads();
    if (t < 16) {
        float s = 0.f, s2 = 0.f;
        #pragma unroll
        for (int j = 0; j < 16; ++j) { s += red[t][j][0]; s2 += red[t][j][1]; }
        float m = s * (1.f / 256.f);
        float var = s2 * (1.f / 256.f) - m * m;
        mrstd[t][0] = m;
        mrstd[t][1] = rsqrtf(var + 1e-5f);
    }
    __syncthreads();
    {
        float g = g2[t], be = be2[t];
        #pragma unroll
        for (int i2 = 0; i2 < 16; ++i2)
            out[(size_t)(b0 + i2) * 256 + t] = (obuf[i2][t] - mrstd[i2][0]) * mrstd[i2][1] * g + be;
    }
}

// ---------------------------------------------------------------------------
extern "C" void kernel_launch(void* const* d_in, const int* in_sizes, int n_in,
                              void* d_out, int out_size, void* d_ws, size_t ws_size,
                              hipStream_t stream)
{
    (void)in_sizes; (void)n_in; (void)out_size; (void)ws_size;
    const float* xu    = (const float*)d_in[0];
    const float* x_ctx = (const float*)d_in[1];
    const float* t_ctx = (const float*)d_in[2];
    const float* freq  = (const float*)d_in[3];
    const float* phase = (const float*)d_in[4];
    const float* Wq    = (const float*)d_in[5];
    const float* Wk    = (const float*)d_in[6];
    const float* Wv    = (const float*)d_in[7];
    const float* Wres  = (const float*)d_in[8];
    const float* bres  = (const float*)d_in[9];
    const float* W1    = (const float*)d_in[10];
    const float* b1    = (const float*)d_in[11];
    const float* W2    = (const float*)d_in[12];
    const float* b2    = (const float*)d_in[13];
    const float* g1    = (const float*)d_in[14];
    const float* be1   = (const float*)d_in[15];
    const float* g2    = (const float*)d_in[16];
    const float* be2   = (const float*)d_in[17];
    float* out = (float*)d_out;

    char* ws = (char*)d_ws;
    u16* WcatT = (u16*)(ws);                    // 262,144 B
    u16* WresT = (u16*)(ws + 262144);           //  65,536
    u16* WvT   = (u16*)(ws + 327680);           // 131,072
    u16* W1T   = (u16*)(ws + 458752);           // 131,072
    u16* W2T   = (u16*)(ws + 589824);           // 131,072  (total 720,896 B)

    hipLaunchKernelGGL(k0_prep, dim3(1408), dim3(256), 0, stream,
                       Wq, Wk, Wv, Wres, W1, W2, WcatT, WresT, WvT, W1T, W2T);
    hipLaunchKernelGGL(kf_fused, dim3(1024), dim3(256), 0, stream,
                       xu, x_ctx, t_ctx, freq, phase,
                       WcatT, WvT, WresT, W1T, W2T,
                       bres, b1, b2, g1, be1, g2, be2, out);
}